// Round 1
// baseline (400.790 us; speedup 1.0000x reference)
//
#include <hip/hip_runtime.h>
#include <math.h>

#define AR_P 48
#define FLEN 168
#define HISTLEN 336
#define ROWS 64       // batch rows per block
#define NTHREADS 512  // 8 waves
#define TPW 21        // forecast steps per wave (168 / 8)

// ws layout (fp32): [0, 8064) Wt[k][t] (transposed coeffs), [8064, 8232) cc[t]

// One wave. Companion-matrix power recurrence:
//   r_0 = phi;  r_{t+1}[k] = r_t[k-1] + r_t[47]*phi[k]   (r_t[-1] == 0)
//   mu_orig[b,t] = cc[t] + sum_k Wt[k,t]*(y[b,k]-mu)   (sigma cancels in W)
__global__ void k_coeffs(const float* __restrict__ phi,
                         const float* __restrict__ bias,
                         const float* __restrict__ mu_p,
                         const float* __restrict__ sigma_p,
                         float* __restrict__ ws) {
    const int k = threadIdx.x;  // 64 threads, 1 wave
    float* Wt = ws;             // [48][168]
    float* cc = ws + AR_P * FLEN;
    const float mu     = mu_p[0];
    const float sigma  = sigma_p[0];
    const float bias_f = bias[0];
    const float phik = (k < AR_P) ? phi[k] : 0.0f;

    float r = phik;     // r_0 = phi
    float csum = 0.0f;  // sum_{m<t} r_m[47]
    for (int t = 0; t < FLEN; ++t) {
        if (k < AR_P) Wt[k * FLEN + t] = r;          // transposed store
        if (k == 0)   cc[t] = bias_f * (1.0f + csum) * sigma + mu;
        float r47 = __shfl(r, AR_P - 1, 64);
        csum += r47;
        float up = __shfl_up(r, 1, 64);
        float rn = (k == 0 ? 0.0f : up) + r47 * phik;
        r = (k < AR_P) ? rn : 0.0f;
    }
}

// Block = 512 threads, 64 rows, ALL 168 t's, plus the logvar fill for its rows.
// All global traffic is coalesced through LDS; enc_l tails read exactly once.
__global__ __launch_bounds__(NTHREADS, 4) void k_main(
    const float* __restrict__ enc_l,
    const float* __restrict__ ws,
    const float* __restrict__ mu_p,
    const float* __restrict__ ls2,
    const float* __restrict__ sg,
    float* __restrict__ out,  // [2*B*168]: mu then logvar
    int B) {
    __shared__ float ym[AR_P][ROWS + 1];   // [48][65] transposed tails, 12.5 KB
    __shared__ float so[FLEN][ROWS + 1];   // [168][65] staged outputs, 43.7 KB

    const int tid = threadIdx.x;
    const int r0  = blockIdx.x * ROWS;
    const int rows_here = min(ROWS, B - r0);
    const float mu = mu_p[0];

    // ---- logvar region: contiguous 43 KB constant fill, fully coalesced ----
    {
        const float lv = ls2[0] + 2.0f * logf(sg[0]);
        const float4 v = make_float4(lv, lv, lv, lv);
        float4* dst = reinterpret_cast<float4*>(
            out + (size_t)B * FLEN + (size_t)r0 * FLEN);
        const int n4 = rows_here * FLEN / 4;  // 2688
        for (int i = tid; i < n4; i += NTHREADS) dst[i] = v;
    }

    // ---- coalesced cooperative load: 64 rows x 48 floats (float4 units) ----
    // id in [0, 768): row = id/12, q = id%12 -> 12 consecutive lanes read one
    // row's contiguous 192 B (3 full 64B lines), minimal line-requests.
    for (int id = tid; id < rows_here * 12; id += NTHREADS) {
        int row = id / 12, q = id - row * 12;
        float4 qv = *reinterpret_cast<const float4*>(
            enc_l + (size_t)(r0 + row) * HISTLEN + (HISTLEN - AR_P) + q * 4);
        ym[q * 4 + 0][row] = qv.x - mu;
        ym[q * 4 + 1][row] = qv.y - mu;
        ym[q * 4 + 2][row] = qv.z - mu;
        ym[q * 4 + 3][row] = qv.w - mu;
    }
    __syncthreads();

    // ---- compute: wave w owns t in [21w, 21w+21), lane = row ----
    // Wt/cc indices wave-uniform -> batched s_load; ym[k][lane] is a
    // conflict-free LDS read (banks = (k+lane)%32, 2 lanes/bank = free).
    {
        const int w = tid >> 6, lane = tid & 63;
        const int t0 = w * TPW;
        const float* Wt = ws;
        const float* cc = ws + AR_P * FLEN;
        float acc[TPW];
#pragma unroll
        for (int j = 0; j < TPW; ++j) acc[j] = cc[t0 + j];
#pragma unroll 4
        for (int k = 0; k < AR_P; ++k) {
            const float y = ym[k][lane];
            const float* wk = Wt + k * FLEN + t0;
#pragma unroll
            for (int j = 0; j < TPW; ++j) acc[j] = fmaf(wk[j], y, acc[j]);
        }
        // stage transposed: banks (t0+j+lane)%32 -> conflict-free
#pragma unroll
        for (int j = 0; j < TPW; ++j) so[t0 + j][lane] = acc[j];
    }
    __syncthreads();

    // ---- mu region: block's span of out is CONTIGUOUS [r0*168, (r0+64)*168)
    // -> fully coalesced dword stores (4 lines/wave-instr, HW minimum).
    {
        float* dst = out + (size_t)r0 * FLEN;
        const int n = rows_here * FLEN;  // 10752
        for (int i = tid; i < n; i += NTHREADS) {
            int row = i / FLEN, t = i - row * FLEN;
            dst[i] = so[t][row];  // banks (t+row)%32: consecutive -> no conflict
        }
    }
}

extern "C" void kernel_launch(void* const* d_in, const int* in_sizes, int n_in,
                              void* d_out, int out_size, void* d_ws, size_t ws_size,
                              hipStream_t stream) {
    const float* enc_l = (const float*)d_in[0];
    // d_in[1..3] = enc_t, enc_w, enc_s (unused by the reference)
    const float* phi  = (const float*)d_in[4];
    const float* bias = (const float*)d_in[5];
    const float* ls2  = (const float*)d_in[6];
    const float* mu   = (const float*)d_in[7];
    const float* sg   = (const float*)d_in[8];
    float* ws  = (float*)d_ws;
    float* out = (float*)d_out;
    const int B = in_sizes[0] / HISTLEN;

    hipLaunchKernelGGL(k_coeffs, dim3(1), dim3(64), 0, stream,
                       phi, bias, mu, sg, ws);
    hipLaunchKernelGGL(k_main, dim3((B + ROWS - 1) / ROWS), dim3(NTHREADS), 0, stream,
                       enc_l, ws, mu, ls2, sg, out, B);
}

// Round 2
// 342.221 us; speedup vs baseline: 1.1711x; 1.1711x over previous
//
#include <hip/hip_runtime.h>
#include <math.h>

#define AR_P 48
#define FLEN 168
#define HISTLEN 336
#define ROWS 128      // batch rows per block (2 per thread)
#define NTHREADS 448  // 7 waves
#define TPW 24        // forecast steps per wave (168/7); 24 floats = 6 float4, 16B-aligned
#define HALF 64

// ws layout (fp32): [0, 8064) Wt[k][t] (transposed coeffs), [8064, 8232) cc[t]

// One wave. Companion-matrix power recurrence:
//   r_0 = phi;  r_{t+1}[k] = r_t[k-1] + r_t[47]*phi[k]   (r_t[-1] == 0)
//   mu_orig[b,t] = cc[t] + sum_k Wt[k,t]*(y[b,k]-mu)   (sigma cancels in W)
__global__ void k_coeffs(const float* __restrict__ phi,
                         const float* __restrict__ bias,
                         const float* __restrict__ mu_p,
                         const float* __restrict__ sigma_p,
                         float* __restrict__ ws) {
    const int k = threadIdx.x;  // 64 threads, 1 wave
    float* Wt = ws;             // [48][168]
    float* cc = ws + AR_P * FLEN;
    const float mu     = mu_p[0];
    const float sigma  = sigma_p[0];
    const float bias_f = bias[0];
    const float phik = (k < AR_P) ? phi[k] : 0.0f;

    float r = phik;     // r_0 = phi
    float csum = 0.0f;  // sum_{m<t} r_m[47]
    for (int t = 0; t < FLEN; ++t) {
        if (k < AR_P) Wt[k * FLEN + t] = r;          // transposed store
        if (k == 0)   cc[t] = bias_f * (1.0f + csum) * sigma + mu;
        float r47 = __shfl(r, AR_P - 1, 64);
        csum += r47;
        float up = __shfl_up(r, 1, 64);
        float rn = (k == 0 ? 0.0f : up) + r47 * phik;
        r = (k < AR_P) ? rn : 0.0f;
    }
}

// Block = 448 threads (7 waves), 128 rows (2 per thread), all 168 t's, fused
// logvar fill. Inner loop: 1 ds_read2 + 6 global_load_dwordx4 per 48 FMAs
// (vs 21 scalar loads : 21 FMAs before) -- kills the W-load latency bound.
__global__ __launch_bounds__(NTHREADS, 4) void k_main(
    const float* __restrict__ enc_l,
    const float* __restrict__ ws,
    const float* __restrict__ mu_p,
    const float* __restrict__ ls2,
    const float* __restrict__ sg,
    float* __restrict__ out,  // [2*B*168]: mu then logvar
    int B) {
    __shared__ float ym[AR_P][ROWS + 2];  // [48][130] transposed tails, 25 KB
    __shared__ float so[FLEN][HALF + 1];  // [168][65] staging, 64 rows/pass, 43.7 KB

    const int tid = threadIdx.x;
    const int r0  = blockIdx.x * ROWS;
    const int rows_here = min(ROWS, B - r0);
    const float mu = mu_p[0];

    // ---- coalesced cooperative tail load: 128 rows x 12 float4 ----
    // (issued first so the load latency overlaps the fill below)
    for (int id = tid; id < rows_here * 12; id += NTHREADS) {
        int row = id / 12, q = id - row * 12;
        float4 qv = *reinterpret_cast<const float4*>(
            enc_l + (size_t)(r0 + row) * HISTLEN + (HISTLEN - AR_P) + q * 4);
        ym[q * 4 + 0][row] = qv.x - mu;
        ym[q * 4 + 1][row] = qv.y - mu;
        ym[q * 4 + 2][row] = qv.z - mu;
        ym[q * 4 + 3][row] = qv.w - mu;
    }

    // ---- logvar region: contiguous constant fill, fully coalesced ----
    {
        const float lv = ls2[0] + 2.0f * logf(sg[0]);
        const float4 v = make_float4(lv, lv, lv, lv);
        float4* dst = reinterpret_cast<float4*>(
            out + (size_t)B * FLEN + (size_t)r0 * FLEN);
        const int n4 = rows_here * FLEN / 4;
        for (int i = tid; i < n4; i += NTHREADS) dst[i] = v;
    }
    __syncthreads();

    // ---- compute: wave w owns t in [24w, 24w+24), lane = row, 2 rows/thread ----
    const int w = tid >> 6, lane = tid & 63;
    const int t0 = w * TPW;
    const float* Wt = ws;
    const float* cc = ws + AR_P * FLEN;

    float acc0[TPW], acc1[TPW];
    {
        const float4* cp = reinterpret_cast<const float4*>(cc + t0);  // 16B-aligned
#pragma unroll
        for (int jq = 0; jq < TPW / 4; ++jq) {
            float4 c4 = cp[jq];
            acc0[jq * 4 + 0] = c4.x; acc1[jq * 4 + 0] = c4.x;
            acc0[jq * 4 + 1] = c4.y; acc1[jq * 4 + 1] = c4.y;
            acc0[jq * 4 + 2] = c4.z; acc1[jq * 4 + 2] = c4.z;
            acc0[jq * 4 + 3] = c4.w; acc1[jq * 4 + 3] = c4.w;
        }
    }
#pragma unroll 2
    for (int k = 0; k < AR_P; ++k) {
        const float y0 = ym[k][lane];        // ds_read2_b32 pair (offset1 = 64)
        const float y1 = ym[k][lane + HALF];
        const float4* wp = reinterpret_cast<const float4*>(Wt + k * FLEN + t0);
#pragma unroll
        for (int jq = 0; jq < TPW / 4; ++jq) {
            float4 w4 = wp[jq];  // global_load_dwordx4, wave-broadcast, L1/L2-hot
            acc0[jq * 4 + 0] = fmaf(w4.x, y0, acc0[jq * 4 + 0]);
            acc0[jq * 4 + 1] = fmaf(w4.y, y0, acc0[jq * 4 + 1]);
            acc0[jq * 4 + 2] = fmaf(w4.z, y0, acc0[jq * 4 + 2]);
            acc0[jq * 4 + 3] = fmaf(w4.w, y0, acc0[jq * 4 + 3]);
            acc1[jq * 4 + 0] = fmaf(w4.x, y1, acc1[jq * 4 + 0]);
            acc1[jq * 4 + 1] = fmaf(w4.y, y1, acc1[jq * 4 + 1]);
            acc1[jq * 4 + 2] = fmaf(w4.z, y1, acc1[jq * 4 + 2]);
            acc1[jq * 4 + 3] = fmaf(w4.w, y1, acc1[jq * 4 + 3]);
        }
    }

    // ---- pass A: stage + store rows [0, 64) ----
#pragma unroll
    for (int j = 0; j < TPW; ++j) so[t0 + j][lane] = acc0[j];
    __syncthreads();
    {
        float* dst = out + (size_t)r0 * FLEN;  // block's contiguous mu span
        const int nA = min(rows_here, HALF) * FLEN;
        for (int i = tid; i < nA; i += NTHREADS) {
            int row = i / FLEN, t = i - row * FLEN;
            dst[i] = so[t][row];  // banks consecutive -> conflict-free
        }
    }
    __syncthreads();

    // ---- pass B: stage + store rows [64, 128) ----
#pragma unroll
    for (int j = 0; j < TPW; ++j) so[t0 + j][lane] = acc1[j];
    __syncthreads();
    if (rows_here > HALF) {
        float* dst = out + ((size_t)r0 + HALF) * FLEN;
        const int nB = (rows_here - HALF) * FLEN;
        for (int i = tid; i < nB; i += NTHREADS) {
            int row = i / FLEN, t = i - row * FLEN;
            dst[i] = so[t][row];
        }
    }
}

extern "C" void kernel_launch(void* const* d_in, const int* in_sizes, int n_in,
                              void* d_out, int out_size, void* d_ws, size_t ws_size,
                              hipStream_t stream) {
    const float* enc_l = (const float*)d_in[0];
    // d_in[1..3] = enc_t, enc_w, enc_s (unused by the reference)
    const float* phi  = (const float*)d_in[4];
    const float* bias = (const float*)d_in[5];
    const float* ls2  = (const float*)d_in[6];
    const float* mu   = (const float*)d_in[7];
    const float* sg   = (const float*)d_in[8];
    float* ws  = (float*)d_ws;
    float* out = (float*)d_out;
    const int B = in_sizes[0] / HISTLEN;

    hipLaunchKernelGGL(k_coeffs, dim3(1), dim3(64), 0, stream,
                       phi, bias, mu, sg, ws);
    hipLaunchKernelGGL(k_main, dim3((B + ROWS - 1) / ROWS), dim3(NTHREADS), 0, stream,
                       enc_l, ws, mu, ls2, sg, out, B);
}

// Round 4
// 305.707 us; speedup vs baseline: 1.3110x; 1.1194x over previous
//
#include <hip/hip_runtime.h>
#include <math.h>

#define AR_P 48
#define FLEN 168
#define HISTLEN 336
#define ROWS 128      // batch rows per block (2 per thread)
#define NTHREADS 448  // 7 waves
#define TPW 24        // forecast steps per wave (168/7); 24 floats = 6 float4, 16B-aligned
#define HALF 64

// ws layout (fp32): [0, 8064) Wt[k][t] (transposed coeffs), [8064, 8232) cc[t]

// One wave. Companion-matrix power recurrence:
//   r_0 = phi;  r_{t+1}[k] = r_t[k-1] + r_t[47]*phi[k]   (r_t[-1] == 0)
//   mu_orig[b,t] = cc[t] + sum_k Wt[k,t]*(y[b,k]-mu)   (sigma cancels in W)
__global__ void k_coeffs(const float* __restrict__ phi,
                         const float* __restrict__ bias,
                         const float* __restrict__ mu_p,
                         const float* __restrict__ sigma_p,
                         float* __restrict__ ws) {
    const int k = threadIdx.x;  // 64 threads, 1 wave
    float* Wt = ws;             // [48][168]
    float* cc = ws + AR_P * FLEN;
    const float mu     = mu_p[0];
    const float sigma  = sigma_p[0];
    const float bias_f = bias[0];
    const float phik = (k < AR_P) ? phi[k] : 0.0f;

    float r = phik;     // r_0 = phi
    float csum = 0.0f;  // sum_{m<t} r_m[47]
    for (int t = 0; t < FLEN; ++t) {
        if (k < AR_P) Wt[k * FLEN + t] = r;          // transposed store
        if (k == 0)   cc[t] = bias_f * (1.0f + csum) * sigma + mu;
        float r47 = __shfl(r, AR_P - 1, 64);
        csum += r47;
        float up = __shfl_up(r, 1, 64);
        float rn = (k == 0 ? 0.0f : up) + r47 * phik;
        r = (k < AR_P) ? rn : 0.0f;
    }
}

// Block = 448 threads (7 waves), 128 rows (2/thread), all 168 t's, fused logvar.
// (a) readfirstlane forces W/cc addresses provably wave-uniform -> scalar
// s_load through the constant cache (no vmcnt latency on the hot loop);
// (b) ym and so share one 43.7 KB LDS buffer (ym dead after k-loop) -> 3
// blocks/CU instead of 2; (c) div-free store loops.
__global__ __launch_bounds__(NTHREADS, 5) void k_main(
    const float* __restrict__ enc_l,
    const float* __restrict__ ws,
    const float* __restrict__ mu_p,
    const float* __restrict__ ls2,
    const float* __restrict__ sg,
    float* __restrict__ out,  // [2*B*168]: mu then logvar
    int B) {
    // union: ym [48][130] (25.0 KB, live until k-loop ends)
    //        so [168][65] (43.7 KB, live after)  -> one 43.7 KB buffer
    __shared__ __align__(16) char smem_raw[FLEN * (HALF + 1) * sizeof(float)];
    float (*ym)[ROWS + 2] = reinterpret_cast<float (*)[ROWS + 2]>(smem_raw);
    float (*so)[HALF + 1] = reinterpret_cast<float (*)[HALF + 1]>(smem_raw);

    const int tid = threadIdx.x;
    const int r0  = blockIdx.x * ROWS;
    const int rows_here = min(ROWS, B - r0);
    const float mu = mu_p[0];

    // ---- coalesced cooperative tail load: 128 rows x 12 float4 ----
    for (int id = tid; id < rows_here * 12; id += NTHREADS) {
        int row = id / 12, q = id - row * 12;
        float4 qv = *reinterpret_cast<const float4*>(
            enc_l + (size_t)(r0 + row) * HISTLEN + (HISTLEN - AR_P) + q * 4);
        ym[q * 4 + 0][row] = qv.x - mu;
        ym[q * 4 + 1][row] = qv.y - mu;
        ym[q * 4 + 2][row] = qv.z - mu;
        ym[q * 4 + 3][row] = qv.w - mu;
    }

    // ---- logvar region: contiguous constant fill, fully coalesced ----
    {
        const float lv = ls2[0] + 2.0f * logf(sg[0]);
        const float4 v = make_float4(lv, lv, lv, lv);
        float4* dst = reinterpret_cast<float4*>(
            out + (size_t)B * FLEN + (size_t)r0 * FLEN);
        const int n4 = rows_here * (FLEN / 4);
        for (int i = tid; i < n4; i += NTHREADS) dst[i] = v;
    }
    __syncthreads();

    // ---- compute: wave w owns t in [24w, 24w+24), lane = row, 2 rows/thread ----
    const int lane = tid & 63;
    // readfirstlane -> compiler-provable wave-uniform: W/cc loads become s_load
    const int t0 = __builtin_amdgcn_readfirstlane((tid >> 6) * TPW);
    const float* Wt = ws;
    const float* cc = ws + AR_P * FLEN;

    float acc0[TPW], acc1[TPW];
    {
        const float4* cp = reinterpret_cast<const float4*>(cc + t0);  // 16B-aligned
#pragma unroll
        for (int jq = 0; jq < TPW / 4; ++jq) {
            float4 c4 = cp[jq];
            acc0[jq * 4 + 0] = c4.x; acc1[jq * 4 + 0] = c4.x;
            acc0[jq * 4 + 1] = c4.y; acc1[jq * 4 + 1] = c4.y;
            acc0[jq * 4 + 2] = c4.z; acc1[jq * 4 + 2] = c4.z;
            acc0[jq * 4 + 3] = c4.w; acc1[jq * 4 + 3] = c4.w;
        }
    }
#pragma unroll 2
    for (int k = 0; k < AR_P; ++k) {
        const float y0 = ym[k][lane];        // 2-way LDS (free)
        const float y1 = ym[k][lane + HALF];
        const float4* wp = reinterpret_cast<const float4*>(Wt + k * FLEN + t0);
#pragma unroll
        for (int jq = 0; jq < TPW / 4; ++jq) {
            float4 w4 = wp[jq];  // uniform addr -> s_load_dwordx4, SGPR operand
            acc0[jq * 4 + 0] = fmaf(w4.x, y0, acc0[jq * 4 + 0]);
            acc0[jq * 4 + 1] = fmaf(w4.y, y0, acc0[jq * 4 + 1]);
            acc0[jq * 4 + 2] = fmaf(w4.z, y0, acc0[jq * 4 + 2]);
            acc0[jq * 4 + 3] = fmaf(w4.w, y0, acc0[jq * 4 + 3]);
            acc1[jq * 4 + 0] = fmaf(w4.x, y1, acc1[jq * 4 + 0]);
            acc1[jq * 4 + 1] = fmaf(w4.y, y1, acc1[jq * 4 + 1]);
            acc1[jq * 4 + 2] = fmaf(w4.z, y1, acc1[jq * 4 + 2]);
            acc1[jq * 4 + 3] = fmaf(w4.w, y1, acc1[jq * 4 + 3]);
        }
    }
    __syncthreads();  // ym dead from here; so may overwrite the shared buffer

    // store index mapping, computed once (div-free afterwards)
    const int row_i = tid / FLEN;           // 0..2
    const int t_i   = tid - row_i * FLEN;
    const int nA = min(rows_here, HALF) * FLEN;

    // ---- pass A: stage + store rows [0, 64) ----
#pragma unroll
    for (int j = 0; j < TPW; ++j) so[t0 + j][lane] = acc0[j];
    __syncthreads();
    {
        float* dst = out + (size_t)r0 * FLEN;  // block's contiguous mu span
        int i = tid, row = row_i, t = t_i;
#pragma unroll 4
        for (int p = 0; p < (HALF * FLEN) / NTHREADS; ++p) {  // 24
            if (i < nA) dst[i] = so[t][row];  // consecutive banks: conflict-free
            i += NTHREADS;
            row += 2; t += NTHREADS - 2 * FLEN;               // +112
            if (t >= FLEN) { t -= FLEN; ++row; }
        }
    }
    __syncthreads();

    // ---- pass B: stage + store rows [64, 128) ----
#pragma unroll
    for (int j = 0; j < TPW; ++j) so[t0 + j][lane] = acc1[j];
    __syncthreads();
    if (rows_here > HALF) {
        float* dst = out + ((size_t)r0 + HALF) * FLEN;
        const int nB = (rows_here - HALF) * FLEN;
        int i = tid, row = row_i, t = t_i;
#pragma unroll 4
        for (int p = 0; p < (HALF * FLEN) / NTHREADS; ++p) {
            if (i < nB) dst[i] = so[t][row];
            i += NTHREADS;
            row += 2; t += NTHREADS - 2 * FLEN;
            if (t >= FLEN) { t -= FLEN; ++row; }
        }
    }
}

extern "C" void kernel_launch(void* const* d_in, const int* in_sizes, int n_in,
                              void* d_out, int out_size, void* d_ws, size_t ws_size,
                              hipStream_t stream) {
    const float* enc_l = (const float*)d_in[0];
    // d_in[1..3] = enc_t, enc_w, enc_s (unused by the reference)
    const float* phi  = (const float*)d_in[4];
    const float* bias = (const float*)d_in[5];
    const float* ls2  = (const float*)d_in[6];
    const float* mu   = (const float*)d_in[7];
    const float* sg   = (const float*)d_in[8];
    float* ws  = (float*)d_ws;
    float* out = (float*)d_out;
    const int B = in_sizes[0] / HISTLEN;

    hipLaunchKernelGGL(k_coeffs, dim3(1), dim3(64), 0, stream,
                       phi, bias, mu, sg, ws);
    hipLaunchKernelGGL(k_main, dim3((B + ROWS - 1) / ROWS), dim3(NTHREADS), 0, stream,
                       enc_l, ws, mu, ls2, sg, out, B);
}